// Round 1
// 151.728 us; speedup vs baseline: 1.0678x; 1.0678x over previous
//
#include <hip/hip_runtime.h>
#include <hip/hip_fp16.h>

// CRF NLL on MI355X — round 10: FUSED single kernel (chunk products + combine).
//
// One block per batch: 512 blocks x 8 waves. Each wave stages+chains 4 chunks
// (identical f16 PACKMM/MFMA pipeline as the verified r9 crf_chunk), then
// stores its 4 fragment products into ITS OWN LDS rows (scales are dead),
// dense SoA layout (quad0 @ lane*16B, quad1 @ 1KiB+lane*16B -> stride-16B,
// conflict-free). One __syncthreads(), then wave 0 runs the 32-step alpha
// chain from LDS (~120cy latency vs ~900cy HBM in the old crf_combine).
// This removes: the 32 MiB ws fragment write + 32 MiB read, the second
// kernel dispatch, and the grid-wide chunk->combine serialization.
// Score/msum/napp per-wave partials pass through tiny ws slot writes
// (drained by the vmcnt(0) before s_barrier; re-read same-CU post-barrier).
//
// Scale 2^-6.5 per applied matrix (exact: added back as napp*6.5*ln2).

typedef __attribute__((ext_vector_type(8)))  _Float16 half8;
typedef __attribute__((ext_vector_type(2)))  _Float16 half2v;
typedef __attribute__((ext_vector_type(16))) float    f32x16;
typedef __attribute__((ext_vector_type(4)))  unsigned uint4v;

#define S_N 1024
#define T_N 32
#define B_N 512
#define L_CH 32
#define C_CH 32
#define SCALE_MUL 0.011048543456039806f   // 2^-6.5 folded into ee
#define SCALE_LOG 4.505456673639645f      // 6.5*ln2 per applied matrix

__device__ __forceinline__ unsigned pkrtz(float lo, float hi) {
    return __builtin_bit_cast(unsigned, __builtin_amdgcn_cvt_pkrtz(lo, hi));
}
__device__ __forceinline__ unsigned pmul(unsigned a, unsigned b) {
    const __half2 r = __builtin_bit_cast(__half2, a) * __builtin_bit_cast(__half2, b);
    return __builtin_bit_cast(unsigned, r);
}
__device__ __forceinline__ half8 mkh8(const unsigned* a) {
    uint4v u = {a[0], a[1], a[2], a[3]};
    return __builtin_bit_cast(half8, u);
}
__device__ __forceinline__ float hlo(unsigned u) {
    return (float)__builtin_bit_cast(half2v, u).x;
}
__device__ __forceinline__ float hhi(unsigned u) {
    return (float)__builtin_bit_cast(half2v, u).y;
}
// PI: involution swapping rows 4-7<->8-11 and 20-23<->24-27
__device__ __forceinline__ int PIx(int x) { return (x & ~12) | ((x & 4) << 1) | ((x & 8) >> 1); }

__global__ __launch_bounds__(512, 4) void crf_fused(
    const float* __restrict__ em, const int* __restrict__ tags,
    const float* __restrict__ mask, const float* __restrict__ trans,
    const float* __restrict__ startT, const float* __restrict__ endT,
    float* __restrict__ wspart, float* __restrict__ out)
{
    __shared__ unsigned elds[C_CH][512];   // 64 KiB: scales, reused for fragments

    const int wib  = threadIdx.x >> 6;     // 0..7
    const int lane = threadIdx.x & 63;
    const int n    = lane & 31;
    const int h    = lane >> 5;
    const int b    = blockIdx.x;
    const int c0   = wib * 4;              // this wave's first chunk

    // ---- stage packed f16 scales for 4 chunks (D-reg-pair order) ----
    #pragma unroll
    for (int q = 0; q < 4; ++q) {
        const float* eq = em + ((size_t)b * S_N + (c0 + q) * L_CH) * T_N;
        unsigned* mq = elds[c0 + q];
        #pragma unroll
        for (int i = 0; i < 8; ++i) {
            const int flat = i * 64 + lane;
            const int r = flat >> 4, m = flat & 15;
            const int base = ((m & 4) << 2) + ((m & 2) << 2) + ((m & 1) << 1) + ((m >> 3) << 2);
            const float2 v = *(const float2*)(eq + r * 32 + base);
            mq[r * 16 + m] = pkrtz(__expf(v.x) * SCALE_MUL, __expf(v.y) * SCALE_MUL);
        }
    }

    // ---- mask ballots (4 chunks) + path-score partial -> ws slots ----
    unsigned mb_[4];
    {
        float vacc = 0.f, macc = 0.f;
        #pragma unroll
        for (int q2 = 0; q2 < 2; ++q2) {
            const int s  = c0 * L_CH + q2 * 64 + lane;
            const float mv = mask[b * S_N + s];
            const unsigned long long mb = __ballot(mv != 0.0f);
            mb_[2 * q2]     = (unsigned)mb;
            mb_[2 * q2 + 1] = (unsigned)(mb >> 32);
            const int tc = tags[b * S_N + s];
            int tp = __shfl_up(tc, 1, 64);
            float val;
            if (lane == 0) {
                if (s == 0) {
                    val = startT[tc] + em[(size_t)b * S_N * T_N + tc];
                } else {
                    tp = tags[b * S_N + s - 1];
                    val = mv * (em[((size_t)b * S_N + s) * T_N + tc] + trans[tp * 32 + tc]);
                }
            } else {
                val = mv * (em[((size_t)b * S_N + s) * T_N + tc] + trans[tp * 32 + tc]);
            }
            vacc += val; macc += mv;
        }
        if (c0 == 0) mb_[0] &= ~1u;        // t=0 has no transition matrix
        #pragma unroll
        for (int d = 32; d > 0; d >>= 1) {
            vacc += __shfl_xor(vacc, d, 64);
            macc += __shfl_xor(macc, d, 64);
        }
        if (lane == 0) {
            float* slot = wspart + (size_t)b * 32 + wib * 4;
            slot[0] = vacc;
            slot[1] = macc;
            slot[2] = (float)(__popc(mb_[0]) + __popc(mb_[1]) +
                              __popc(mb_[2]) + __popc(mb_[3]));
        }
    }

    // ---- loop-invariant A fragments: f16(exp(trans)), PI-permuted cols ----
    unsigned A1[4], A2[4];
    #pragma unroll
    for (int j = 0; j < 4; ++j) {
        const int k1 = PIx(8 * h + 2 * j);
        const int k2 = PIx(16 + 8 * h + 2 * j);
        A1[j] = pkrtz(__expf(trans[n * 32 + k1]), __expf(trans[n * 32 + k1 + 1]));
        A2[j] = pkrtz(__expf(trans[n * 32 + k2]), __expf(trans[n * 32 + k2 + 1]));
    }
    const half8 A1v = mkh8(A1), A2v = mkh8(A2);
    const f32x16 Zacc = {};

    // ---- 4 chain states: identity in C layout ----
    f32x16 D0, D1, D2, D3;
    #pragma unroll
    for (int i = 0; i < 16; ++i) {
        const int row = (i & 3) + 8 * (i >> 2) + 4 * h;
        const float v = (row == n) ? 1.0f : 0.0f;
        D0[i] = v; D1[i] = v; D2[i] = v; D3[i] = v;
    }

    const unsigned* m0 = elds[c0];
    const unsigned* m1 = elds[c0 + 1];
    const unsigned* m2 = elds[c0 + 2];
    const unsigned* m3 = elds[c0 + 3];

    // pack + 2 MFMAs for one chain (loads already issued)
    #define PACKMM(D, su, sv) { \
        unsigned S[8]; \
        S[0] = pmul(pkrtz(D[0],  D[1]),  su.x); \
        S[1] = pmul(pkrtz(D[2],  D[3]),  su.y); \
        S[2] = pmul(pkrtz(D[4],  D[5]),  su.z); \
        S[3] = pmul(pkrtz(D[6],  D[7]),  su.w); \
        S[4] = pmul(pkrtz(D[8],  D[9]),  sv.x); \
        S[5] = pmul(pkrtz(D[10], D[11]), sv.y); \
        S[6] = pmul(pkrtz(D[12], D[13]), sv.z); \
        S[7] = pmul(pkrtz(D[14], D[15]), sv.w); \
        f32x16 t_ = __builtin_amdgcn_mfma_f32_32x32x16_f16(A1v, mkh8(&S[0]), Zacc, 0, 0, 0); \
        D = __builtin_amdgcn_mfma_f32_32x32x16_f16(A2v, mkh8(&S[4]), t_, 0, 0, 0); \
    }
    // fallback masked step (load inside; rare path)
    #define STEP1(D, mq, r_) { \
        const uint4 su = *(const uint4*)((mq) + (r_) * 16 + h * 8); \
        const uint4 sv = *(const uint4*)((mq) + (r_) * 16 + h * 8 + 4); \
        PACKMM(D, su, sv) \
    }

    const bool allclean =
        ((mb_[0] | (c0 == 0 ? 1u : 0u)) == 0xFFFFFFFFu) &&
        (mb_[1] == 0xFFFFFFFFu) && (mb_[2] == 0xFFFFFFFFu) && (mb_[3] == 0xFFFFFFFFu);

    if (allclean) {
        #pragma unroll 2
        for (int r = L_CH - 1; r >= 1; --r) {
            // phase 1: all 8 loads issue back-to-back
            const uint4 su0 = *(const uint4*)(m0 + r * 16 + h * 8);
            const uint4 sv0 = *(const uint4*)(m0 + r * 16 + h * 8 + 4);
            const uint4 su1 = *(const uint4*)(m1 + r * 16 + h * 8);
            const uint4 sv1 = *(const uint4*)(m1 + r * 16 + h * 8 + 4);
            const uint4 su2 = *(const uint4*)(m2 + r * 16 + h * 8);
            const uint4 sv2 = *(const uint4*)(m2 + r * 16 + h * 8 + 4);
            const uint4 su3 = *(const uint4*)(m3 + r * 16 + h * 8);
            const uint4 sv3 = *(const uint4*)(m3 + r * 16 + h * 8 + 4);
            // phase 2: chain q's MFMA shadow filled by chain q+1's packs
            PACKMM(D0, su0, sv0)
            PACKMM(D1, su1, sv1)
            PACKMM(D2, su2, sv2)
            PACKMM(D3, su3, sv3)
        }
        if (mb_[0] & 1u) STEP1(D0, m0, 0);   // c0==0 has bit0 cleared
        if (mb_[1] & 1u) STEP1(D1, m1, 0);
        if (mb_[2] & 1u) STEP1(D2, m2, 0);
        if (mb_[3] & 1u) STEP1(D3, m3, 0);
    } else {
        for (int r = L_CH - 1; r >= 0; --r) {
            if ((mb_[0] >> r) & 1u) STEP1(D0, m0, r);
            if ((mb_[1] >> r) & 1u) STEP1(D1, m1, r);
            if ((mb_[2] >> r) & 1u) STEP1(D2, m2, r);
            if ((mb_[3] >> r) & 1u) STEP1(D3, m3, r);
        }
    }
    #undef PACKMM
    #undef STEP1

    // ---- fragment store: own LDS rows (scales dead), dense SoA layout ----
    // quad0 of lane L at dword L*4, quad1 at dword 256+L*4 -> stride-16B,
    // conflict-free ds_write_b128 / ds_read_b128 on both sides.
    #define STOREF(D, q_) { \
        unsigned* dst = elds[c0 + (q_)]; \
        ((uint4*)dst)[lane]      = make_uint4(pkrtz(D[0], D[1]),   pkrtz(D[2], D[3]), \
                                              pkrtz(D[4], D[5]),   pkrtz(D[6], D[7])); \
        ((uint4*)dst)[64 + lane] = make_uint4(pkrtz(D[8], D[9]),   pkrtz(D[10], D[11]), \
                                              pkrtz(D[12], D[13]), pkrtz(D[14], D[15])); \
    }
    STOREF(D0, 0) STOREF(D1, 1) STOREF(D2, 2) STOREF(D3, 3)
    #undef STOREF

    __syncthreads();                        // all fragments + ws slots visible

    if (wib != 0) return;

    // ---- combine: 32-step alpha row-vector chain over LDS fragments ----
    int idxA[8], idxB[8];
    #pragma unroll
    for (int j = 0; j < 8; ++j) {
        idxA[j] = PIx(8 * h + j);
        idxB[j] = PIx(16 + 8 * h + j);
    }

    float a0 = startT[n] + em[(size_t)b * S_N * T_N + n];
    float mx = a0;
    #pragma unroll
    for (int d = 16; d > 0; d >>= 1) mx = fmaxf(mx, __shfl_xor(mx, d, 32));
    float A = __expf(a0 - mx);
    float Lacc = mx;
    float scor = (lane < 8) ? wspart[(size_t)b * 32 + lane * 4]     : 0.0f;
    float msum = (lane < 8) ? wspart[(size_t)b * 32 + lane * 4 + 1] : 0.0f;
    float ntot = (lane < 8) ? wspart[(size_t)b * 32 + lane * 4 + 2] : 0.0f;

    for (int c = 0; c < C_CH; ++c) {
        const unsigned* ch = elds[c];
        const uint4 qa = *(const uint4*)(ch + lane * 4);
        const uint4 qb = *(const uint4*)(ch + 256 + lane * 4);

        float p0 = 0.f, p1 = 0.f, p2 = 0.f, p3 = 0.f;
        p0 = fmaf(__shfl(A, idxA[0], 32), hlo(qa.x), p0);
        p1 = fmaf(__shfl(A, idxA[1], 32), hhi(qa.x), p1);
        p2 = fmaf(__shfl(A, idxA[2], 32), hlo(qa.y), p2);
        p3 = fmaf(__shfl(A, idxA[3], 32), hhi(qa.y), p3);
        p0 = fmaf(__shfl(A, idxA[4], 32), hlo(qa.z), p0);
        p1 = fmaf(__shfl(A, idxA[5], 32), hhi(qa.z), p1);
        p2 = fmaf(__shfl(A, idxA[6], 32), hlo(qa.w), p2);
        p3 = fmaf(__shfl(A, idxA[7], 32), hhi(qa.w), p3);
        p0 = fmaf(__shfl(A, idxB[0], 32), hlo(qb.x), p0);
        p1 = fmaf(__shfl(A, idxB[1], 32), hhi(qb.x), p1);
        p2 = fmaf(__shfl(A, idxB[2], 32), hlo(qb.y), p2);
        p3 = fmaf(__shfl(A, idxB[3], 32), hhi(qb.y), p3);
        p0 = fmaf(__shfl(A, idxB[4], 32), hlo(qb.z), p0);
        p1 = fmaf(__shfl(A, idxB[5], 32), hhi(qb.z), p1);
        p2 = fmaf(__shfl(A, idxB[6], 32), hlo(qb.w), p2);
        p3 = fmaf(__shfl(A, idxB[7], 32), hhi(qb.w), p3);
        float part = (p0 + p1) + (p2 + p3);
        part += __shfl_xor(part, 32);       // fold half-wave partials

        float mm = part;
        #pragma unroll
        for (int d = 16; d > 0; d >>= 1) mm = fmaxf(mm, __shfl_xor(mm, d, 32));
        A = part / mm;
        Lacc += __logf(mm);
    }

    float v = A * __expf(endT[n]);
    #pragma unroll
    for (int d = 16; d > 0; d >>= 1) {
        v    += __shfl_xor(v, d, 32);
        ntot += __shfl_xor(ntot, d, 32);
        msum += __shfl_xor(msum, d, 32);
        scor += __shfl_xor(scor, d, 32);
    }
    if (lane == 0) {
        const int len = (int)(msum + 0.5f);
        const int lt  = tags[b * S_N + len - 1];
        const float res = Lacc + __logf(v) + ntot * SCALE_LOG - endT[lt] - scor;
        atomicAdd(out, res);
    }
}

extern "C" void kernel_launch(void* const* d_in, const int* in_sizes, int n_in,
                              void* d_out, int out_size, void* d_ws, size_t ws_size,
                              hipStream_t stream) {
    const float* em     = (const float*)d_in[0];
    const int*   tags   = (const int*)  d_in[1];
    const float* mask   = (const float*)d_in[2];
    const float* trans  = (const float*)d_in[3];
    const float* startT = (const float*)d_in[4];
    const float* endT   = (const float*)d_in[5];

    hipMemsetAsync(d_out, 0, sizeof(float), stream);

    // one block per batch: 8 waves x 4 chunks; 64 KiB LDS -> 2 blocks/CU
    hipLaunchKernelGGL(crf_fused, dim3(B_N), dim3(512), 0, stream,
                       em, tags, mask, trans, startT, endT,
                       (float*)d_ws, (float*)d_out);
}

// Round 2
// 150.017 us; speedup vs baseline: 1.0800x; 1.0114x over previous
//
#include <hip/hip_runtime.h>
#include <hip/hip_fp16.h>

// CRF NLL on MI355X — round 11: fused kernel at FULL occupancy.
//
// r10 fused chunk-products + combine into one kernel (one block per batch)
// and killed the 64 MiB ws round-trip, but 512-thread blocks @ 64 KiB LDS
// gave only 16/32 waves per CU (4/SIMD) -> latency-bound at VALUBusy 31%.
// r11: 1024-thread blocks, 16 waves x 2 chunks/wave. LDS unchanged (64 KiB
// is the fragment-buffer lower bound), still 2 blocks/CU, but now 32
// waves/CU = 100% occupancy (8/SIMD). Per-wave state halves (2 chain D's),
// so the 64-VGPR / 8-wave regalloc bound holds (__launch_bounds__(1024,8)).
// Grid remains exactly resident: 512 blocks / 2-per-CU / 256 CU, no tail.
//
// Pipeline per wave: stage packed f16 scales for its 2 chunks (exp folded,
// scale 2^-6.5/matrix, exact: added back as napp*6.5*ln2), then 31 steps of
// {4x ds_read_b128 -> pack (8 pkrtz + 8 pk_mul) -> 2x mfma_32x32x16_f16}
// per chain, PI-aligned so C/D order == next B order (zero cross-lane).
// Fragments stored to own LDS rows (scales dead), one barrier, wave 0 runs
// the 32-step alpha chain from LDS. Score/msum/napp partials via tiny ws
// slot writes (drained by the barrier's vmcnt(0); same-CU L2 re-read).

typedef __attribute__((ext_vector_type(8)))  _Float16 half8;
typedef __attribute__((ext_vector_type(2)))  _Float16 half2v;
typedef __attribute__((ext_vector_type(16))) float    f32x16;
typedef __attribute__((ext_vector_type(4)))  unsigned uint4v;

#define S_N 1024
#define T_N 32
#define B_N 512
#define L_CH 32
#define C_CH 32
#define SCALE_MUL 0.011048543456039806f   // 2^-6.5 folded into ee
#define SCALE_LOG 4.505456673639645f      // 6.5*ln2 per applied matrix

__device__ __forceinline__ unsigned pkrtz(float lo, float hi) {
    return __builtin_bit_cast(unsigned, __builtin_amdgcn_cvt_pkrtz(lo, hi));
}
__device__ __forceinline__ unsigned pmul(unsigned a, unsigned b) {
    const __half2 r = __builtin_bit_cast(__half2, a) * __builtin_bit_cast(__half2, b);
    return __builtin_bit_cast(unsigned, r);
}
__device__ __forceinline__ half8 mkh8(const unsigned* a) {
    uint4v u = {a[0], a[1], a[2], a[3]};
    return __builtin_bit_cast(half8, u);
}
__device__ __forceinline__ float hlo(unsigned u) {
    return (float)__builtin_bit_cast(half2v, u).x;
}
__device__ __forceinline__ float hhi(unsigned u) {
    return (float)__builtin_bit_cast(half2v, u).y;
}
// PI: involution swapping rows 4-7<->8-11 and 20-23<->24-27
__device__ __forceinline__ int PIx(int x) { return (x & ~12) | ((x & 4) << 1) | ((x & 8) >> 1); }

__global__ __launch_bounds__(1024, 8) void crf_fused(
    const float* __restrict__ em, const int* __restrict__ tags,
    const float* __restrict__ mask, const float* __restrict__ trans,
    const float* __restrict__ startT, const float* __restrict__ endT,
    float* __restrict__ wspart, float* __restrict__ out)
{
    __shared__ unsigned elds[C_CH][512];   // 64 KiB: scales, reused for fragments

    const int wib  = threadIdx.x >> 6;     // 0..15
    const int lane = threadIdx.x & 63;
    const int n    = lane & 31;
    const int h    = lane >> 5;
    const int b    = blockIdx.x;
    const int c0   = wib * 2;              // this wave's first chunk

    // ---- stage packed f16 scales for 2 chunks (D-reg-pair order) ----
    #pragma unroll
    for (int q = 0; q < 2; ++q) {
        const float* eq = em + ((size_t)b * S_N + (c0 + q) * L_CH) * T_N;
        unsigned* mq = elds[c0 + q];
        #pragma unroll
        for (int i = 0; i < 8; ++i) {
            const int flat = i * 64 + lane;
            const int r = flat >> 4, m = flat & 15;
            const int base = ((m & 4) << 2) + ((m & 2) << 2) + ((m & 1) << 1) + ((m >> 3) << 2);
            const float2 v = *(const float2*)(eq + r * 32 + base);
            mq[r * 16 + m] = pkrtz(__expf(v.x) * SCALE_MUL, __expf(v.y) * SCALE_MUL);
        }
    }

    // ---- mask ballot (2 chunks = 64 positions) + path-score partial ----
    unsigned mb_[2];
    {
        const int s  = c0 * L_CH + lane;
        const float mv = mask[b * S_N + s];
        const unsigned long long mb = __ballot(mv != 0.0f);
        mb_[0] = (unsigned)mb;
        mb_[1] = (unsigned)(mb >> 32);
        const int tc = tags[b * S_N + s];
        int tp = __shfl_up(tc, 1, 64);
        float val;
        if (lane == 0) {
            if (s == 0) {
                val = startT[tc] + em[(size_t)b * S_N * T_N + tc];
            } else {
                tp = tags[b * S_N + s - 1];
                val = mv * (em[((size_t)b * S_N + s) * T_N + tc] + trans[tp * 32 + tc]);
            }
        } else {
            val = mv * (em[((size_t)b * S_N + s) * T_N + tc] + trans[tp * 32 + tc]);
        }
        float vacc = val, macc = mv;
        if (c0 == 0) mb_[0] &= ~1u;        // t=0 has no transition matrix
        #pragma unroll
        for (int d = 32; d > 0; d >>= 1) {
            vacc += __shfl_xor(vacc, d, 64);
            macc += __shfl_xor(macc, d, 64);
        }
        if (lane == 0) {
            float* slot = wspart + (size_t)b * 64 + wib * 4;
            slot[0] = vacc;
            slot[1] = macc;
            slot[2] = (float)(__popc(mb_[0]) + __popc(mb_[1]));
        }
    }

    // ---- loop-invariant A fragments: f16(exp(trans)), PI-permuted cols ----
    unsigned A1[4], A2[4];
    #pragma unroll
    for (int j = 0; j < 4; ++j) {
        const int k1 = PIx(8 * h + 2 * j);
        const int k2 = PIx(16 + 8 * h + 2 * j);
        A1[j] = pkrtz(__expf(trans[n * 32 + k1]), __expf(trans[n * 32 + k1 + 1]));
        A2[j] = pkrtz(__expf(trans[n * 32 + k2]), __expf(trans[n * 32 + k2 + 1]));
    }
    const half8 A1v = mkh8(A1), A2v = mkh8(A2);
    const f32x16 Zacc = {};

    // ---- 2 chain states: identity in C layout ----
    f32x16 D0, D1;
    #pragma unroll
    for (int i = 0; i < 16; ++i) {
        const int row = (i & 3) + 8 * (i >> 2) + 4 * h;
        const float v = (row == n) ? 1.0f : 0.0f;
        D0[i] = v; D1[i] = v;
    }

    const unsigned* m0 = elds[c0];
    const unsigned* m1 = elds[c0 + 1];

    // pack + 2 MFMAs for one chain (loads already issued)
    #define PACKMM(D, su, sv) { \
        unsigned S[8]; \
        S[0] = pmul(pkrtz(D[0],  D[1]),  su.x); \
        S[1] = pmul(pkrtz(D[2],  D[3]),  su.y); \
        S[2] = pmul(pkrtz(D[4],  D[5]),  su.z); \
        S[3] = pmul(pkrtz(D[6],  D[7]),  su.w); \
        S[4] = pmul(pkrtz(D[8],  D[9]),  sv.x); \
        S[5] = pmul(pkrtz(D[10], D[11]), sv.y); \
        S[6] = pmul(pkrtz(D[12], D[13]), sv.z); \
        S[7] = pmul(pkrtz(D[14], D[15]), sv.w); \
        f32x16 t_ = __builtin_amdgcn_mfma_f32_32x32x16_f16(A1v, mkh8(&S[0]), Zacc, 0, 0, 0); \
        D = __builtin_amdgcn_mfma_f32_32x32x16_f16(A2v, mkh8(&S[4]), t_, 0, 0, 0); \
    }
    // fallback masked step (load inside; rare path)
    #define STEP1(D, mq, r_) { \
        const uint4 su = *(const uint4*)((mq) + (r_) * 16 + h * 8); \
        const uint4 sv = *(const uint4*)((mq) + (r_) * 16 + h * 8 + 4); \
        PACKMM(D, su, sv) \
    }

    const bool allclean =
        ((mb_[0] | (c0 == 0 ? 1u : 0u)) == 0xFFFFFFFFu) &&
        (mb_[1] == 0xFFFFFFFFu);

    if (allclean) {
        #pragma unroll 2
        for (int r = L_CH - 1; r >= 1; --r) {
            // phase 1: all 4 loads issue back-to-back
            const uint4 su0 = *(const uint4*)(m0 + r * 16 + h * 8);
            const uint4 sv0 = *(const uint4*)(m0 + r * 16 + h * 8 + 4);
            const uint4 su1 = *(const uint4*)(m1 + r * 16 + h * 8);
            const uint4 sv1 = *(const uint4*)(m1 + r * 16 + h * 8 + 4);
            // phase 2: chain 1's packs fill chain 0's MFMA shadow
            PACKMM(D0, su0, sv0)
            PACKMM(D1, su1, sv1)
        }
        if (mb_[0] & 1u) STEP1(D0, m0, 0);   // c0==0 has bit0 cleared
        if (mb_[1] & 1u) STEP1(D1, m1, 0);
    } else {
        for (int r = L_CH - 1; r >= 0; --r) {
            if ((mb_[0] >> r) & 1u) STEP1(D0, m0, r);
            if ((mb_[1] >> r) & 1u) STEP1(D1, m1, r);
        }
    }
    #undef PACKMM
    #undef STEP1

    // ---- fragment store: own LDS rows (scales dead), dense SoA layout ----
    // quad0 of lane L at dword L*4, quad1 at dword 256+L*4 -> stride-16B,
    // conflict-free ds_write_b128 / ds_read_b128 on both sides.
    #define STOREF(D, q_) { \
        unsigned* dst = elds[c0 + (q_)]; \
        ((uint4*)dst)[lane]      = make_uint4(pkrtz(D[0], D[1]),   pkrtz(D[2], D[3]), \
                                              pkrtz(D[4], D[5]),   pkrtz(D[6], D[7])); \
        ((uint4*)dst)[64 + lane] = make_uint4(pkrtz(D[8], D[9]),   pkrtz(D[10], D[11]), \
                                              pkrtz(D[12], D[13]), pkrtz(D[14], D[15])); \
    }
    STOREF(D0, 0) STOREF(D1, 1)
    #undef STOREF

    __syncthreads();                        // all fragments + ws slots visible

    if (wib != 0) return;

    // ---- combine: 32-step alpha row-vector chain over LDS fragments ----
    int idxA[8], idxB[8];
    #pragma unroll
    for (int j = 0; j < 8; ++j) {
        idxA[j] = PIx(8 * h + j);
        idxB[j] = PIx(16 + 8 * h + j);
    }

    float a0 = startT[n] + em[(size_t)b * S_N * T_N + n];
    float mx = a0;
    #pragma unroll
    for (int d = 16; d > 0; d >>= 1) mx = fmaxf(mx, __shfl_xor(mx, d, 32));
    float A = __expf(a0 - mx);
    float Lacc = mx;
    float scor = (lane < 16) ? wspart[(size_t)b * 64 + lane * 4]     : 0.0f;
    float msum = (lane < 16) ? wspart[(size_t)b * 64 + lane * 4 + 1] : 0.0f;
    float ntot = (lane < 16) ? wspart[(size_t)b * 64 + lane * 4 + 2] : 0.0f;

    for (int c = 0; c < C_CH; ++c) {
        const unsigned* ch = elds[c];
        const uint4 qa = *(const uint4*)(ch + lane * 4);
        const uint4 qb = *(const uint4*)(ch + 256 + lane * 4);

        float p0 = 0.f, p1 = 0.f, p2 = 0.f, p3 = 0.f;
        p0 = fmaf(__shfl(A, idxA[0], 32), hlo(qa.x), p0);
        p1 = fmaf(__shfl(A, idxA[1], 32), hhi(qa.x), p1);
        p2 = fmaf(__shfl(A, idxA[2], 32), hlo(qa.y), p2);
        p3 = fmaf(__shfl(A, idxA[3], 32), hhi(qa.y), p3);
        p0 = fmaf(__shfl(A, idxA[4], 32), hlo(qa.z), p0);
        p1 = fmaf(__shfl(A, idxA[5], 32), hhi(qa.z), p1);
        p2 = fmaf(__shfl(A, idxA[6], 32), hlo(qa.w), p2);
        p3 = fmaf(__shfl(A, idxA[7], 32), hhi(qa.w), p3);
        p0 = fmaf(__shfl(A, idxB[0], 32), hlo(qb.x), p0);
        p1 = fmaf(__shfl(A, idxB[1], 32), hhi(qb.x), p1);
        p2 = fmaf(__shfl(A, idxB[2], 32), hlo(qb.y), p2);
        p3 = fmaf(__shfl(A, idxB[3], 32), hhi(qb.y), p3);
        p0 = fmaf(__shfl(A, idxB[4], 32), hlo(qb.z), p0);
        p1 = fmaf(__shfl(A, idxB[5], 32), hhi(qb.z), p1);
        p2 = fmaf(__shfl(A, idxB[6], 32), hlo(qb.w), p2);
        p3 = fmaf(__shfl(A, idxB[7], 32), hhi(qb.w), p3);
        float part = (p0 + p1) + (p2 + p3);
        part += __shfl_xor(part, 32);       // fold half-wave partials

        float mm = part;
        #pragma unroll
        for (int d = 16; d > 0; d >>= 1) mm = fmaxf(mm, __shfl_xor(mm, d, 32));
        A = part / mm;
        Lacc += __logf(mm);
    }

    float v = A * __expf(endT[n]);
    #pragma unroll
    for (int d = 16; d > 0; d >>= 1) {
        v    += __shfl_xor(v, d, 32);
        ntot += __shfl_xor(ntot, d, 32);
        msum += __shfl_xor(msum, d, 32);
        scor += __shfl_xor(scor, d, 32);
    }
    if (lane == 0) {
        const int len = (int)(msum + 0.5f);
        const int lt  = tags[b * S_N + len - 1];
        const float res = Lacc + __logf(v) + ntot * SCALE_LOG - endT[lt] - scor;
        atomicAdd(out, res);
    }
}

extern "C" void kernel_launch(void* const* d_in, const int* in_sizes, int n_in,
                              void* d_out, int out_size, void* d_ws, size_t ws_size,
                              hipStream_t stream) {
    const float* em     = (const float*)d_in[0];
    const int*   tags   = (const int*)  d_in[1];
    const float* mask   = (const float*)d_in[2];
    const float* trans  = (const float*)d_in[3];
    const float* startT = (const float*)d_in[4];
    const float* endT   = (const float*)d_in[5];

    hipMemsetAsync(d_out, 0, sizeof(float), stream);

    // one block per batch: 16 waves x 2 chunks; 64 KiB LDS -> 2 blocks/CU,
    // 32 waves/CU = 100% occupancy, whole grid resident (512 = 256 CU x 2)
    hipLaunchKernelGGL(crf_fused, dim3(B_N), dim3(1024), 0, stream,
                       em, tags, mask, trans, startT, endT,
                       (float*)d_ws, (float*)d_out);
}

// Round 3
// 148.177 us; speedup vs baseline: 1.0934x; 1.0124x over previous
//
#include <hip/hip_runtime.h>
#include <hip/hip_fp16.h>

// CRF NLL on MI355X — round 12: pipelined staging under the MFMA chain.
//
// r11 post-mortem: doubling occupancy (29->49%) changed nothing -> TLP was
// never the limit. Correct MFMA accounting (32x32x16 f16 = 32cy/SIMD) shows
// the chain phase is ~13us of saturated MFMA pipe; the other ~45us is the
// emissions staging phase running at 1.2-1.8 TB/s because stage and chain
// were SEQUENTIAL per wave (register-batched float2 loads -> latency bound).
//
// r12: 512-thread blocks (8 waves x 4 chunks), __launch_bounds__(512,4)
// -> 128-VGPR cap, 2 blocks/CU. Per wave, chunk-pair software pipeline:
//   load(P, pair0) ; ballot/score + A-setup (overlap) ; pack(pair0)
//   load(P, pair1)            <- 32 VGPRs in flight
//   chain2(pair0)             <- ~3400cy of MFMA hides the HBM latency
//   pack(pair1) ; chain2(pair1) ; storeF ; barrier ; wave0 combine (LDS)
// Loads are now LINEAR 16B dwordx4 (4 instr/chunk, was 8x permuted float2);
// the D-reg-pair permutation moved to the LDS STORE address:
// m = ((f&1)<<3)|(f&6), the two packed u32s are adjacent -> ds_write_b64,
// conflict-free. Chain inner loop is r11's verified 2-chain PACKMM/MFMA.
// Scale 2^-6.5 per applied matrix (exact: added back as napp*6.5*ln2).

typedef __attribute__((ext_vector_type(8)))  _Float16 half8;
typedef __attribute__((ext_vector_type(2)))  _Float16 half2v;
typedef __attribute__((ext_vector_type(16))) float    f32x16;
typedef __attribute__((ext_vector_type(4)))  unsigned uint4v;

#define S_N 1024
#define T_N 32
#define B_N 512
#define L_CH 32
#define C_CH 32
#define SCALE_MUL 0.011048543456039806f   // 2^-6.5 folded into ee
#define SCALE_LOG 4.505456673639645f      // 6.5*ln2 per applied matrix

__device__ __forceinline__ unsigned pkrtz(float lo, float hi) {
    return __builtin_bit_cast(unsigned, __builtin_amdgcn_cvt_pkrtz(lo, hi));
}
__device__ __forceinline__ unsigned pmul(unsigned a, unsigned b) {
    const __half2 r = __builtin_bit_cast(__half2, a) * __builtin_bit_cast(__half2, b);
    return __builtin_bit_cast(unsigned, r);
}
__device__ __forceinline__ half8 mkh8(const unsigned* a) {
    uint4v u = {a[0], a[1], a[2], a[3]};
    return __builtin_bit_cast(half8, u);
}
__device__ __forceinline__ float hlo(unsigned u) {
    return (float)__builtin_bit_cast(half2v, u).x;
}
__device__ __forceinline__ float hhi(unsigned u) {
    return (float)__builtin_bit_cast(half2v, u).y;
}
// PI: involution swapping rows 4-7<->8-11 and 20-23<->24-27
__device__ __forceinline__ int PIx(int x) { return (x & ~12) | ((x & 4) << 1) | ((x & 8) >> 1); }

__device__ __forceinline__ f32x16 packmm(const f32x16& D, uint4 su, uint4 sv,
                                         half8 A1v, half8 A2v) {
    unsigned S[8];
    S[0] = pmul(pkrtz(D[0],  D[1]),  su.x);
    S[1] = pmul(pkrtz(D[2],  D[3]),  su.y);
    S[2] = pmul(pkrtz(D[4],  D[5]),  su.z);
    S[3] = pmul(pkrtz(D[6],  D[7]),  su.w);
    S[4] = pmul(pkrtz(D[8],  D[9]),  sv.x);
    S[5] = pmul(pkrtz(D[10], D[11]), sv.y);
    S[6] = pmul(pkrtz(D[12], D[13]), sv.z);
    S[7] = pmul(pkrtz(D[14], D[15]), sv.w);
    const f32x16 Z = {};
    f32x16 t = __builtin_amdgcn_mfma_f32_32x32x16_f16(A1v, mkh8(&S[0]), Z, 0, 0, 0);
    return   __builtin_amdgcn_mfma_f32_32x32x16_f16(A2v, mkh8(&S[4]), t, 0, 0, 0);
}
__device__ __forceinline__ void step1(f32x16& D, const unsigned* mq, int r, int h,
                                      half8 A1v, half8 A2v) {
    const uint4 su = *(const uint4*)(mq + r * 16 + h * 8);
    const uint4 sv = *(const uint4*)(mq + r * 16 + h * 8 + 4);
    D = packmm(D, su, sv, A1v, A2v);
}

template<bool CLEAN>
__device__ __forceinline__ void chain2(const unsigned* m0, const unsigned* m1,
                                       f32x16& D0, f32x16& D1,
                                       unsigned mb0, unsigned mb1, int h,
                                       half8 A1v, half8 A2v) {
    if (CLEAN) {
        #pragma unroll 2
        for (int r = L_CH - 1; r >= 1; --r) {
            // all 4 loads issue back-to-back; chain1's packs fill chain0's MFMA shadow
            const uint4 su0 = *(const uint4*)(m0 + r * 16 + h * 8);
            const uint4 sv0 = *(const uint4*)(m0 + r * 16 + h * 8 + 4);
            const uint4 su1 = *(const uint4*)(m1 + r * 16 + h * 8);
            const uint4 sv1 = *(const uint4*)(m1 + r * 16 + h * 8 + 4);
            D0 = packmm(D0, su0, sv0, A1v, A2v);
            D1 = packmm(D1, su1, sv1, A1v, A2v);
        }
        if (mb0 & 1u) step1(D0, m0, 0, h, A1v, A2v);   // chunk 0 has bit0 cleared
        if (mb1 & 1u) step1(D1, m1, 0, h, A1v, A2v);
    } else {
        for (int r = L_CH - 1; r >= 0; --r) {
            if ((mb0 >> r) & 1u) step1(D0, m0, r, h, A1v, A2v);
            if ((mb1 >> r) & 1u) step1(D1, m1, r, h, A1v, A2v);
        }
    }
}

__global__ __launch_bounds__(512, 4) void crf_fused(
    const float* __restrict__ em, const int* __restrict__ tags,
    const float* __restrict__ mask, const float* __restrict__ trans,
    const float* __restrict__ startT, const float* __restrict__ endT,
    float* __restrict__ wspart, float* __restrict__ out)
{
    __shared__ unsigned elds[C_CH][512];   // 64 KiB: scales, reused for fragments

    const int wib  = threadIdx.x >> 6;     // 0..7
    const int lane = threadIdx.x & 63;
    const int n    = lane & 31;
    const int h    = lane >> 5;
    const int b    = blockIdx.x;
    const int c0   = wib * 4;              // this wave's first chunk

    // ---- issue pair-0 emission loads immediately (16B/lane, linear) ----
    float4 P0[4], P1[4];
    {
        const float4* eq0 = (const float4*)(em + ((size_t)b * S_N + (c0 + 0) * L_CH) * T_N);
        const float4* eq1 = (const float4*)(em + ((size_t)b * S_N + (c0 + 1) * L_CH) * T_N);
        #pragma unroll
        for (int i = 0; i < 4; ++i) P0[i] = eq0[i * 64 + lane];
        #pragma unroll
        for (int i = 0; i < 4; ++i) P1[i] = eq1[i * 64 + lane];
    }

    // ---- mask ballots (4 chunks = 128 positions) + path-score partial ----
    // (these scattered loads overlap the emission prefetch in flight)
    unsigned mb_[4];
    {
        float vacc = 0.f, macc = 0.f;
        #pragma unroll
        for (int q2 = 0; q2 < 2; ++q2) {
            const int s  = c0 * L_CH + q2 * 64 + lane;
            const float mv = mask[b * S_N + s];
            const unsigned long long mb = __ballot(mv != 0.0f);
            mb_[2 * q2]     = (unsigned)mb;
            mb_[2 * q2 + 1] = (unsigned)(mb >> 32);
            const int tc = tags[b * S_N + s];
            int tp = __shfl_up(tc, 1, 64);
            float val;
            if (lane == 0) {
                if (s == 0) {
                    val = startT[tc] + em[(size_t)b * S_N * T_N + tc];
                } else {
                    tp = tags[b * S_N + s - 1];
                    val = mv * (em[((size_t)b * S_N + s) * T_N + tc] + trans[tp * 32 + tc]);
                }
            } else {
                val = mv * (em[((size_t)b * S_N + s) * T_N + tc] + trans[tp * 32 + tc]);
            }
            vacc += val; macc += mv;
        }
        if (c0 == 0) mb_[0] &= ~1u;        // t=0 has no transition matrix
        #pragma unroll
        for (int d = 32; d > 0; d >>= 1) {
            vacc += __shfl_xor(vacc, d, 64);
            macc += __shfl_xor(macc, d, 64);
        }
        if (lane == 0) {
            float* slot = wspart + (size_t)b * 32 + wib * 4;
            slot[0] = vacc;
            slot[1] = macc;
            slot[2] = (float)(__popc(mb_[0]) + __popc(mb_[1]) +
                              __popc(mb_[2]) + __popc(mb_[3]));
        }
    }

    // ---- loop-invariant A fragments: f16(exp(trans)), PI-permuted cols ----
    unsigned A1[4], A2[4];
    #pragma unroll
    for (int j = 0; j < 4; ++j) {
        const int k1 = PIx(8 * h + 2 * j);
        const int k2 = PIx(16 + 8 * h + 2 * j);
        A1[j] = pkrtz(__expf(trans[n * 32 + k1]), __expf(trans[n * 32 + k1 + 1]));
        A2[j] = pkrtz(__expf(trans[n * 32 + k2]), __expf(trans[n * 32 + k2 + 1]));
    }
    const half8 A1v = mkh8(A1), A2v = mkh8(A2);

    // pack loaded f32 quads -> f16 scale pairs in D-reg-pair LDS order.
    // lane's float4 covers floats [f*4, f*4+3] of row r=f>>3; the two packed
    // u32s land at slots m and m+1, m = ((f&1)<<3)|(f&6)  (inverse of the
    // old per-slot base permutation) -> single 8B-aligned ds_write_b64.
    #define PACKQ(P, qc) { \
        unsigned* mq = elds[qc]; \
        _Pragma("unroll") \
        for (int i = 0; i < 4; ++i) { \
            const int f = i * 64 + lane; \
            const int r_ = f >> 3; \
            const int m_ = ((f & 1) << 3) | (f & 6); \
            const unsigned pk0 = pkrtz(__expf(P[i].x) * SCALE_MUL, __expf(P[i].y) * SCALE_MUL); \
            const unsigned pk1 = pkrtz(__expf(P[i].z) * SCALE_MUL, __expf(P[i].w) * SCALE_MUL); \
            *(uint2*)(mq + r_ * 16 + m_) = make_uint2(pk0, pk1); \
        } }

    PACKQ(P0, c0)
    PACKQ(P1, c0 + 1)

    // ---- issue pair-1 loads NOW; they fly under chain2(pair0) ----
    {
        const float4* eq2 = (const float4*)(em + ((size_t)b * S_N + (c0 + 2) * L_CH) * T_N);
        const float4* eq3 = (const float4*)(em + ((size_t)b * S_N + (c0 + 3) * L_CH) * T_N);
        #pragma unroll
        for (int i = 0; i < 4; ++i) P0[i] = eq2[i * 64 + lane];
        #pragma unroll
        for (int i = 0; i < 4; ++i) P1[i] = eq3[i * 64 + lane];
    }

    // ---- chain states: identity in C layout ----
    f32x16 D0, D1;
    #pragma unroll
    for (int i = 0; i < 16; ++i) {
        const int row = (i & 3) + 8 * (i >> 2) + 4 * h;
        const float v = (row == n) ? 1.0f : 0.0f;
        D0[i] = v; D1[i] = v;
    }

    const bool clean0 =
        ((mb_[0] | (c0 == 0 ? 1u : 0u)) == 0xFFFFFFFFu) && (mb_[1] == 0xFFFFFFFFu);
    const bool clean1 = (mb_[2] == 0xFFFFFFFFu) && (mb_[3] == 0xFFFFFFFFu);

    if (clean0) chain2<true >(elds[c0], elds[c0 + 1], D0, D1, mb_[0], mb_[1], h, A1v, A2v);
    else        chain2<false>(elds[c0], elds[c0 + 1], D0, D1, mb_[0], mb_[1], h, A1v, A2v);

    // fragment store: own LDS rows (scales dead), dense SoA, stride-16B
    #define STOREF(D, qc) { \
        unsigned* dst = elds[qc]; \
        ((uint4*)dst)[lane]      = make_uint4(pkrtz(D[0], D[1]),   pkrtz(D[2], D[3]), \
                                              pkrtz(D[4], D[5]),   pkrtz(D[6], D[7])); \
        ((uint4*)dst)[64 + lane] = make_uint4(pkrtz(D[8], D[9]),   pkrtz(D[10], D[11]), \
                                              pkrtz(D[12], D[13]), pkrtz(D[14], D[15])); \
    }
    STOREF(D0, c0) STOREF(D1, c0 + 1)

    // ---- pair 1: pack (consumes prefetch), re-init D, chain, store ----
    PACKQ(P0, c0 + 2)
    PACKQ(P1, c0 + 3)
    #pragma unroll
    for (int i = 0; i < 16; ++i) {
        const int row = (i & 3) + 8 * (i >> 2) + 4 * h;
        const float v = (row == n) ? 1.0f : 0.0f;
        D0[i] = v; D1[i] = v;
    }
    if (clean1) chain2<true >(elds[c0 + 2], elds[c0 + 3], D0, D1, mb_[2], mb_[3], h, A1v, A2v);
    else        chain2<false>(elds[c0 + 2], elds[c0 + 3], D0, D1, mb_[2], mb_[3], h, A1v, A2v);
    STOREF(D0, c0 + 2) STOREF(D1, c0 + 3)
    #undef STOREF
    #undef PACKQ

    __syncthreads();                        // all fragments + ws slots visible

    if (wib != 0) return;

    // ---- combine: 32-step alpha row-vector chain over LDS fragments ----
    int idxA[8], idxB[8];
    #pragma unroll
    for (int j = 0; j < 8; ++j) {
        idxA[j] = PIx(8 * h + j);
        idxB[j] = PIx(16 + 8 * h + j);
    }

    float a0 = startT[n] + em[(size_t)b * S_N * T_N + n];
    float mx = a0;
    #pragma unroll
    for (int d = 16; d > 0; d >>= 1) mx = fmaxf(mx, __shfl_xor(mx, d, 32));
    float A = __expf(a0 - mx);
    float Lacc = mx;
    float scor = (lane < 8) ? wspart[(size_t)b * 32 + lane * 4]     : 0.0f;
    float msum = (lane < 8) ? wspart[(size_t)b * 32 + lane * 4 + 1] : 0.0f;
    float ntot = (lane < 8) ? wspart[(size_t)b * 32 + lane * 4 + 2] : 0.0f;

    for (int c = 0; c < C_CH; ++c) {
        const unsigned* ch = elds[c];
        const uint4 qa = *(const uint4*)(ch + lane * 4);
        const uint4 qb = *(const uint4*)(ch + 256 + lane * 4);

        float p0 = 0.f, p1 = 0.f, p2 = 0.f, p3 = 0.f;
        p0 = fmaf(__shfl(A, idxA[0], 32), hlo(qa.x), p0);
        p1 = fmaf(__shfl(A, idxA[1], 32), hhi(qa.x), p1);
        p2 = fmaf(__shfl(A, idxA[2], 32), hlo(qa.y), p2);
        p3 = fmaf(__shfl(A, idxA[3], 32), hhi(qa.y), p3);
        p0 = fmaf(__shfl(A, idxA[4], 32), hlo(qa.z), p0);
        p1 = fmaf(__shfl(A, idxA[5], 32), hhi(qa.z), p1);
        p2 = fmaf(__shfl(A, idxA[6], 32), hlo(qa.w), p2);
        p3 = fmaf(__shfl(A, idxA[7], 32), hhi(qa.w), p3);
        p0 = fmaf(__shfl(A, idxB[0], 32), hlo(qb.x), p0);
        p1 = fmaf(__shfl(A, idxB[1], 32), hhi(qb.x), p1);
        p2 = fmaf(__shfl(A, idxB[2], 32), hlo(qb.y), p2);
        p3 = fmaf(__shfl(A, idxB[3], 32), hhi(qb.y), p3);
        p0 = fmaf(__shfl(A, idxB[4], 32), hlo(qb.z), p0);
        p1 = fmaf(__shfl(A, idxB[5], 32), hhi(qb.z), p1);
        p2 = fmaf(__shfl(A, idxB[6], 32), hlo(qb.w), p2);
        p3 = fmaf(__shfl(A, idxB[7], 32), hhi(qb.w), p3);
        float part = (p0 + p1) + (p2 + p3);
        part += __shfl_xor(part, 32);       // fold half-wave partials

        float mm = part;
        #pragma unroll
        for (int d = 16; d > 0; d >>= 1) mm = fmaxf(mm, __shfl_xor(mm, d, 32));
        A = part / mm;
        Lacc += __logf(mm);
    }

    float v = A * __expf(endT[n]);
    #pragma unroll
    for (int d = 16; d > 0; d >>= 1) {
        v    += __shfl_xor(v, d, 32);
        ntot += __shfl_xor(ntot, d, 32);
        msum += __shfl_xor(msum, d, 32);
        scor += __shfl_xor(scor, d, 32);
    }
    if (lane == 0) {
        const int len = (int)(msum + 0.5f);
        const int lt  = tags[b * S_N + len - 1];
        const float res = Lacc + __logf(v) + ntot * SCALE_LOG - endT[lt] - scor;
        atomicAdd(out, res);
    }
}

extern "C" void kernel_launch(void* const* d_in, const int* in_sizes, int n_in,
                              void* d_out, int out_size, void* d_ws, size_t ws_size,
                              hipStream_t stream) {
    const float* em     = (const float*)d_in[0];
    const int*   tags   = (const int*)  d_in[1];
    const float* mask   = (const float*)d_in[2];
    const float* trans  = (const float*)d_in[3];
    const float* startT = (const float*)d_in[4];
    const float* endT   = (const float*)d_in[5];

    hipMemsetAsync(d_out, 0, sizeof(float), stream);

    // one block per batch: 8 waves x 4 chunks; 64 KiB LDS -> 2 blocks/CU
    hipLaunchKernelGGL(crf_fused, dim3(B_N), dim3(512), 0, stream,
                       em, tags, mask, trans, startT, endT,
                       (float*)d_ws, (float*)d_out);
}

// Round 4
// 146.268 us; speedup vs baseline: 1.1077x; 1.0130x over previous
//
#include <hip/hip_runtime.h>
#include <hip/hip_fp16.h>

// CRF NLL on MI355X — round 13: r12 pipeline with the register budget FIXED.
//
// r12 post-mortem: the pair-1 prefetch (32 VGPRs live across chain2) was
// SPILLED — compiler chose 64 VGPR despite launch_bounds allowing 128
// (WRITE_SIZE 82KB -> 2.1MB = 8B/thread of scratch; kernel 66->91us).
// launch_bounds' 2nd arg is only a MINIMUM waves/EU; the allocator still
// targeted 8/SIMD. Fix: amdgpu_waves_per_eu(4,4) pins occupancy at the
// LDS-imposed ceiling (64KiB -> 2 blocks/CU -> 4 waves/SIMD) and frees
// up to 128 VGPRs. This round changes ONLY the register-budget attribute;
// structure is r12's: per wave {load pair0 -> ballot/score -> pack pair0 ->
// load pair1 -> chain2(pair0) [loads fly under ~3400cy of MFMA] ->
// pack pair1 -> chain2(pair1) -> storeF}; barrier; wave0 combines from LDS.
// Scale 2^-6.5 per applied matrix (exact: added back as napp*6.5*ln2).

typedef __attribute__((ext_vector_type(8)))  _Float16 half8;
typedef __attribute__((ext_vector_type(2)))  _Float16 half2v;
typedef __attribute__((ext_vector_type(16))) float    f32x16;
typedef __attribute__((ext_vector_type(4)))  unsigned uint4v;

#define S_N 1024
#define T_N 32
#define B_N 512
#define L_CH 32
#define C_CH 32
#define SCALE_MUL 0.011048543456039806f   // 2^-6.5 folded into ee
#define SCALE_LOG 4.505456673639645f      // 6.5*ln2 per applied matrix

__device__ __forceinline__ unsigned pkrtz(float lo, float hi) {
    return __builtin_bit_cast(unsigned, __builtin_amdgcn_cvt_pkrtz(lo, hi));
}
__device__ __forceinline__ unsigned pmul(unsigned a, unsigned b) {
    const __half2 r = __builtin_bit_cast(__half2, a) * __builtin_bit_cast(__half2, b);
    return __builtin_bit_cast(unsigned, r);
}
__device__ __forceinline__ half8 mkh8(const unsigned* a) {
    uint4v u = {a[0], a[1], a[2], a[3]};
    return __builtin_bit_cast(half8, u);
}
__device__ __forceinline__ float hlo(unsigned u) {
    return (float)__builtin_bit_cast(half2v, u).x;
}
__device__ __forceinline__ float hhi(unsigned u) {
    return (float)__builtin_bit_cast(half2v, u).y;
}
// PI: involution swapping rows 4-7<->8-11 and 20-23<->24-27
__device__ __forceinline__ int PIx(int x) { return (x & ~12) | ((x & 4) << 1) | ((x & 8) >> 1); }

__device__ __forceinline__ f32x16 packmm(const f32x16& D, uint4 su, uint4 sv,
                                         half8 A1v, half8 A2v) {
    unsigned S[8];
    S[0] = pmul(pkrtz(D[0],  D[1]),  su.x);
    S[1] = pmul(pkrtz(D[2],  D[3]),  su.y);
    S[2] = pmul(pkrtz(D[4],  D[5]),  su.z);
    S[3] = pmul(pkrtz(D[6],  D[7]),  su.w);
    S[4] = pmul(pkrtz(D[8],  D[9]),  sv.x);
    S[5] = pmul(pkrtz(D[10], D[11]), sv.y);
    S[6] = pmul(pkrtz(D[12], D[13]), sv.z);
    S[7] = pmul(pkrtz(D[14], D[15]), sv.w);
    const f32x16 Z = {};
    f32x16 t = __builtin_amdgcn_mfma_f32_32x32x16_f16(A1v, mkh8(&S[0]), Z, 0, 0, 0);
    return   __builtin_amdgcn_mfma_f32_32x32x16_f16(A2v, mkh8(&S[4]), t, 0, 0, 0);
}
__device__ __forceinline__ void step1(f32x16& D, const unsigned* mq, int r, int h,
                                      half8 A1v, half8 A2v) {
    const uint4 su = *(const uint4*)(mq + r * 16 + h * 8);
    const uint4 sv = *(const uint4*)(mq + r * 16 + h * 8 + 4);
    D = packmm(D, su, sv, A1v, A2v);
}

template<bool CLEAN>
__device__ __forceinline__ void chain2(const unsigned* m0, const unsigned* m1,
                                       f32x16& D0, f32x16& D1,
                                       unsigned mb0, unsigned mb1, int h,
                                       half8 A1v, half8 A2v) {
    if (CLEAN) {
        #pragma unroll 2
        for (int r = L_CH - 1; r >= 1; --r) {
            // all 4 loads issue back-to-back; chain1's packs fill chain0's MFMA shadow
            const uint4 su0 = *(const uint4*)(m0 + r * 16 + h * 8);
            const uint4 sv0 = *(const uint4*)(m0 + r * 16 + h * 8 + 4);
            const uint4 su1 = *(const uint4*)(m1 + r * 16 + h * 8);
            const uint4 sv1 = *(const uint4*)(m1 + r * 16 + h * 8 + 4);
            D0 = packmm(D0, su0, sv0, A1v, A2v);
            D1 = packmm(D1, su1, sv1, A1v, A2v);
        }
        if (mb0 & 1u) step1(D0, m0, 0, h, A1v, A2v);   // chunk 0 has bit0 cleared
        if (mb1 & 1u) step1(D1, m1, 0, h, A1v, A2v);
    } else {
        for (int r = L_CH - 1; r >= 0; --r) {
            if ((mb0 >> r) & 1u) step1(D0, m0, r, h, A1v, A2v);
            if ((mb1 >> r) & 1u) step1(D1, m1, r, h, A1v, A2v);
        }
    }
}

__global__ __attribute__((amdgpu_flat_work_group_size(512, 512),
                          amdgpu_waves_per_eu(4, 4)))
void crf_fused(
    const float* __restrict__ em, const int* __restrict__ tags,
    const float* __restrict__ mask, const float* __restrict__ trans,
    const float* __restrict__ startT, const float* __restrict__ endT,
    float* __restrict__ wspart, float* __restrict__ out)
{
    __shared__ unsigned elds[C_CH][512];   // 64 KiB: scales, reused for fragments

    const int wib  = threadIdx.x >> 6;     // 0..7
    const int lane = threadIdx.x & 63;
    const int n    = lane & 31;
    const int h    = lane >> 5;
    const int b    = blockIdx.x;
    const int c0   = wib * 4;              // this wave's first chunk

    // ---- issue pair-0 emission loads immediately (16B/lane, linear) ----
    float4 P0[4], P1[4];
    {
        const float4* eq0 = (const float4*)(em + ((size_t)b * S_N + (c0 + 0) * L_CH) * T_N);
        const float4* eq1 = (const float4*)(em + ((size_t)b * S_N + (c0 + 1) * L_CH) * T_N);
        #pragma unroll
        for (int i = 0; i < 4; ++i) P0[i] = eq0[i * 64 + lane];
        #pragma unroll
        for (int i = 0; i < 4; ++i) P1[i] = eq1[i * 64 + lane];
    }

    // ---- mask ballots (4 chunks = 128 positions) + path-score partial ----
    // (these scattered loads overlap the emission prefetch in flight)
    unsigned mb_[4];
    {
        float vacc = 0.f, macc = 0.f;
        #pragma unroll
        for (int q2 = 0; q2 < 2; ++q2) {
            const int s  = c0 * L_CH + q2 * 64 + lane;
            const float mv = mask[b * S_N + s];
            const unsigned long long mb = __ballot(mv != 0.0f);
            mb_[2 * q2]     = (unsigned)mb;
            mb_[2 * q2 + 1] = (unsigned)(mb >> 32);
            const int tc = tags[b * S_N + s];
            int tp = __shfl_up(tc, 1, 64);
            float val;
            if (lane == 0) {
                if (s == 0) {
                    val = startT[tc] + em[(size_t)b * S_N * T_N + tc];
                } else {
                    tp = tags[b * S_N + s - 1];
                    val = mv * (em[((size_t)b * S_N + s) * T_N + tc] + trans[tp * 32 + tc]);
                }
            } else {
                val = mv * (em[((size_t)b * S_N + s) * T_N + tc] + trans[tp * 32 + tc]);
            }
            vacc += val; macc += mv;
        }
        if (c0 == 0) mb_[0] &= ~1u;        // t=0 has no transition matrix
        #pragma unroll
        for (int d = 32; d > 0; d >>= 1) {
            vacc += __shfl_xor(vacc, d, 64);
            macc += __shfl_xor(macc, d, 64);
        }
        if (lane == 0) {
            float* slot = wspart + (size_t)b * 32 + wib * 4;
            slot[0] = vacc;
            slot[1] = macc;
            slot[2] = (float)(__popc(mb_[0]) + __popc(mb_[1]) +
                              __popc(mb_[2]) + __popc(mb_[3]));
        }
    }

    // ---- loop-invariant A fragments: f16(exp(trans)), PI-permuted cols ----
    unsigned A1[4], A2[4];
    #pragma unroll
    for (int j = 0; j < 4; ++j) {
        const int k1 = PIx(8 * h + 2 * j);
        const int k2 = PIx(16 + 8 * h + 2 * j);
        A1[j] = pkrtz(__expf(trans[n * 32 + k1]), __expf(trans[n * 32 + k1 + 1]));
        A2[j] = pkrtz(__expf(trans[n * 32 + k2]), __expf(trans[n * 32 + k2 + 1]));
    }
    const half8 A1v = mkh8(A1), A2v = mkh8(A2);

    // pack loaded f32 quads -> f16 scale pairs in D-reg-pair LDS order.
    // lane's float4 covers floats [f*4, f*4+3] of row r=f>>3; the two packed
    // u32s land at slots m and m+1, m = ((f&1)<<3)|(f&6)  (inverse of the
    // old per-slot base permutation) -> single 8B-aligned ds_write_b64.
    #define PACKQ(P, qc) { \
        unsigned* mq = elds[qc]; \
        _Pragma("unroll") \
        for (int i = 0; i < 4; ++i) { \
            const int f = i * 64 + lane; \
            const int r_ = f >> 3; \
            const int m_ = ((f & 1) << 3) | (f & 6); \
            const unsigned pk0 = pkrtz(__expf(P[i].x) * SCALE_MUL, __expf(P[i].y) * SCALE_MUL); \
            const unsigned pk1 = pkrtz(__expf(P[i].z) * SCALE_MUL, __expf(P[i].w) * SCALE_MUL); \
            *(uint2*)(mq + r_ * 16 + m_) = make_uint2(pk0, pk1); \
        } }

    PACKQ(P0, c0)
    PACKQ(P1, c0 + 1)

    // ---- issue pair-1 loads NOW; they fly under chain2(pair0) ----
    {
        const float4* eq2 = (const float4*)(em + ((size_t)b * S_N + (c0 + 2) * L_CH) * T_N);
        const float4* eq3 = (const float4*)(em + ((size_t)b * S_N + (c0 + 3) * L_CH) * T_N);
        #pragma unroll
        for (int i = 0; i < 4; ++i) P0[i] = eq2[i * 64 + lane];
        #pragma unroll
        for (int i = 0; i < 4; ++i) P1[i] = eq3[i * 64 + lane];
    }

    // ---- chain states: identity in C layout ----
    f32x16 D0, D1;
    #pragma unroll
    for (int i = 0; i < 16; ++i) {
        const int row = (i & 3) + 8 * (i >> 2) + 4 * h;
        const float v = (row == n) ? 1.0f : 0.0f;
        D0[i] = v; D1[i] = v;
    }

    const bool clean0 =
        ((mb_[0] | (c0 == 0 ? 1u : 0u)) == 0xFFFFFFFFu) && (mb_[1] == 0xFFFFFFFFu);
    const bool clean1 = (mb_[2] == 0xFFFFFFFFu) && (mb_[3] == 0xFFFFFFFFu);

    if (clean0) chain2<true >(elds[c0], elds[c0 + 1], D0, D1, mb_[0], mb_[1], h, A1v, A2v);
    else        chain2<false>(elds[c0], elds[c0 + 1], D0, D1, mb_[0], mb_[1], h, A1v, A2v);

    // fragment store: own LDS rows (scales dead), dense SoA, stride-16B
    #define STOREF(D, qc) { \
        unsigned* dst = elds[qc]; \
        ((uint4*)dst)[lane]      = make_uint4(pkrtz(D[0], D[1]),   pkrtz(D[2], D[3]), \
                                              pkrtz(D[4], D[5]),   pkrtz(D[6], D[7])); \
        ((uint4*)dst)[64 + lane] = make_uint4(pkrtz(D[8], D[9]),   pkrtz(D[10], D[11]), \
                                              pkrtz(D[12], D[13]), pkrtz(D[14], D[15])); \
    }
    STOREF(D0, c0) STOREF(D1, c0 + 1)

    // ---- pair 1: pack (consumes prefetch), re-init D, chain, store ----
    PACKQ(P0, c0 + 2)
    PACKQ(P1, c0 + 3)
    #pragma unroll
    for (int i = 0; i < 16; ++i) {
        const int row = (i & 3) + 8 * (i >> 2) + 4 * h;
        const float v = (row == n) ? 1.0f : 0.0f;
        D0[i] = v; D1[i] = v;
    }
    if (clean1) chain2<true >(elds[c0 + 2], elds[c0 + 3], D0, D1, mb_[2], mb_[3], h, A1v, A2v);
    else        chain2<false>(elds[c0 + 2], elds[c0 + 3], D0, D1, mb_[2], mb_[3], h, A1v, A2v);
    STOREF(D0, c0 + 2) STOREF(D1, c0 + 3)
    #undef STOREF
    #undef PACKQ

    __syncthreads();                        // all fragments + ws slots visible

    if (wib != 0) return;

    // ---- combine: 32-step alpha row-vector chain over LDS fragments ----
    int idxA[8], idxB[8];
    #pragma unroll
    for (int j = 0; j < 8; ++j) {
        idxA[j] = PIx(8 * h + j);
        idxB[j] = PIx(16 + 8 * h + j);
    }

    float a0 = startT[n] + em[(size_t)b * S_N * T_N + n];
    float mx = a0;
    #pragma unroll
    for (int d = 16; d > 0; d >>= 1) mx = fmaxf(mx, __shfl_xor(mx, d, 32));
    float A = __expf(a0 - mx);
    float Lacc = mx;
    float scor = (lane < 8) ? wspart[(size_t)b * 32 + lane * 4]     : 0.0f;
    float msum = (lane < 8) ? wspart[(size_t)b * 32 + lane * 4 + 1] : 0.0f;
    float ntot = (lane < 8) ? wspart[(size_t)b * 32 + lane * 4 + 2] : 0.0f;

    for (int c = 0; c < C_CH; ++c) {
        const unsigned* ch = elds[c];
        const uint4 qa = *(const uint4*)(ch + lane * 4);
        const uint4 qb = *(const uint4*)(ch + 256 + lane * 4);

        float p0 = 0.f, p1 = 0.f, p2 = 0.f, p3 = 0.f;
        p0 = fmaf(__shfl(A, idxA[0], 32), hlo(qa.x), p0);
        p1 = fmaf(__shfl(A, idxA[1], 32), hhi(qa.x), p1);
        p2 = fmaf(__shfl(A, idxA[2], 32), hlo(qa.y), p2);
        p3 = fmaf(__shfl(A, idxA[3], 32), hhi(qa.y), p3);
        p0 = fmaf(__shfl(A, idxA[4], 32), hlo(qa.z), p0);
        p1 = fmaf(__shfl(A, idxA[5], 32), hhi(qa.z), p1);
        p2 = fmaf(__shfl(A, idxA[6], 32), hlo(qa.w), p2);
        p3 = fmaf(__shfl(A, idxA[7], 32), hhi(qa.w), p3);
        p0 = fmaf(__shfl(A, idxB[0], 32), hlo(qb.x), p0);
        p1 = fmaf(__shfl(A, idxB[1], 32), hhi(qb.x), p1);
        p2 = fmaf(__shfl(A, idxB[2], 32), hlo(qb.y), p2);
        p3 = fmaf(__shfl(A, idxB[3], 32), hhi(qb.y), p3);
        p0 = fmaf(__shfl(A, idxB[4], 32), hlo(qb.z), p0);
        p1 = fmaf(__shfl(A, idxB[5], 32), hhi(qb.z), p1);
        p2 = fmaf(__shfl(A, idxB[6], 32), hlo(qb.w), p2);
        p3 = fmaf(__shfl(A, idxB[7], 32), hhi(qb.w), p3);
        float part = (p0 + p1) + (p2 + p3);
        part += __shfl_xor(part, 32);       // fold half-wave partials

        float mm = part;
        #pragma unroll
        for (int d = 16; d > 0; d >>= 1) mm = fmaxf(mm, __shfl_xor(mm, d, 32));
        A = part / mm;
        Lacc += __logf(mm);
    }

    float v = A * __expf(endT[n]);
    #pragma unroll
    for (int d = 16; d > 0; d >>= 1) {
        v    += __shfl_xor(v, d, 32);
        ntot += __shfl_xor(ntot, d, 32);
        msum += __shfl_xor(msum, d, 32);
        scor += __shfl_xor(scor, d, 32);
    }
    if (lane == 0) {
        const int len = (int)(msum + 0.5f);
        const int lt  = tags[b * S_N + len - 1];
        const float res = Lacc + __logf(v) + ntot * SCALE_LOG - endT[lt] - scor;
        atomicAdd(out, res);
    }
}

extern "C" void kernel_launch(void* const* d_in, const int* in_sizes, int n_in,
                              void* d_out, int out_size, void* d_ws, size_t ws_size,
                              hipStream_t stream) {
    const float* em     = (const float*)d_in[0];
    const int*   tags   = (const int*)  d_in[1];
    const float* mask   = (const float*)d_in[2];
    const float* trans  = (const float*)d_in[3];
    const float* startT = (const float*)d_in[4];
    const float* endT   = (const float*)d_in[5];

    hipMemsetAsync(d_out, 0, sizeof(float), stream);

    // one block per batch: 8 waves x 4 chunks; 64 KiB LDS -> 2 blocks/CU
    hipLaunchKernelGGL(crf_fused, dim3(B_N), dim3(512), 0, stream,
                       em, tags, mask, trans, startT, endT,
                       (float*)d_ws, (float*)d_out);
}

// Round 6
// 142.203 us; speedup vs baseline: 1.1394x; 1.0286x over previous
//
#include <hip/hip_runtime.h>
#include <hip/hip_fp16.h>

// CRF NLL on MI355X — round 15: combine with PERIODIC (every-4) normalization.
//
// r14 post-mortem: lag-2 deferred norm is dynamically UNSTABLE — the
// log-magnitude recursion l_{c+1} = l_c - l_{c-2} + f has complex roots of
// modulus 1.15 -> oscillatory exponential amplification (~88x over 32 iters)
// of chunk-magnitude fluctuations -> f32 overflow -> rcp(inf)=0 -> inf*0=NaN.
// Lag-1 is only marginally stable (modulus 1, random-walk ~ sqrt(c)).
//
// r15: normalize every 4th iteration, applied IMMEDIATELY (no feedback
// loop, unconditionally stable). After each norm A <= 1; per-step growth
// is hard-bounded by ln(32*65504)=14.6, so worst intermediate is
// e^58.3 ~ 2e25 << f32 max. Lacc accumulates exactly the applied logs.
// This removes the ~600cy serial shfl_xor max-reduce + rcp + logf from
// 24 of 32 tail iterations (x4 unroll makes the predicate static).
// Everything outside the combine loop is byte-identical to r13 (passed).
//
// Scale 2^-6.5 per applied matrix (exact: added back as napp*6.5*ln2).

typedef __attribute__((ext_vector_type(8)))  _Float16 half8;
typedef __attribute__((ext_vector_type(2)))  _Float16 half2v;
typedef __attribute__((ext_vector_type(16))) float    f32x16;
typedef __attribute__((ext_vector_type(4)))  unsigned uint4v;

#define S_N 1024
#define T_N 32
#define B_N 512
#define L_CH 32
#define C_CH 32
#define SCALE_MUL 0.011048543456039806f   // 2^-6.5 folded into ee
#define SCALE_LOG 4.505456673639645f      // 6.5*ln2 per applied matrix

__device__ __forceinline__ unsigned pkrtz(float lo, float hi) {
    return __builtin_bit_cast(unsigned, __builtin_amdgcn_cvt_pkrtz(lo, hi));
}
__device__ __forceinline__ unsigned pmul(unsigned a, unsigned b) {
    const __half2 r = __builtin_bit_cast(__half2, a) * __builtin_bit_cast(__half2, b);
    return __builtin_bit_cast(unsigned, r);
}
__device__ __forceinline__ half8 mkh8(const unsigned* a) {
    uint4v u = {a[0], a[1], a[2], a[3]};
    return __builtin_bit_cast(half8, u);
}
__device__ __forceinline__ float hlo(unsigned u) {
    return (float)__builtin_bit_cast(half2v, u).x;
}
__device__ __forceinline__ float hhi(unsigned u) {
    return (float)__builtin_bit_cast(half2v, u).y;
}
// PI: involution swapping rows 4-7<->8-11 and 20-23<->24-27
__device__ __forceinline__ int PIx(int x) { return (x & ~12) | ((x & 4) << 1) | ((x & 8) >> 1); }

__device__ __forceinline__ f32x16 packmm(const f32x16& D, uint4 su, uint4 sv,
                                         half8 A1v, half8 A2v) {
    unsigned S[8];
    S[0] = pmul(pkrtz(D[0],  D[1]),  su.x);
    S[1] = pmul(pkrtz(D[2],  D[3]),  su.y);
    S[2] = pmul(pkrtz(D[4],  D[5]),  su.z);
    S[3] = pmul(pkrtz(D[6],  D[7]),  su.w);
    S[4] = pmul(pkrtz(D[8],  D[9]),  sv.x);
    S[5] = pmul(pkrtz(D[10], D[11]), sv.y);
    S[6] = pmul(pkrtz(D[12], D[13]), sv.z);
    S[7] = pmul(pkrtz(D[14], D[15]), sv.w);
    const f32x16 Z = {};
    f32x16 t = __builtin_amdgcn_mfma_f32_32x32x16_f16(A1v, mkh8(&S[0]), Z, 0, 0, 0);
    return   __builtin_amdgcn_mfma_f32_32x32x16_f16(A2v, mkh8(&S[4]), t, 0, 0, 0);
}
__device__ __forceinline__ void step1(f32x16& D, const unsigned* mq, int r, int h,
                                      half8 A1v, half8 A2v) {
    const uint4 su = *(const uint4*)(mq + r * 16 + h * 8);
    const uint4 sv = *(const uint4*)(mq + r * 16 + h * 8 + 4);
    D = packmm(D, su, sv, A1v, A2v);
}

template<bool CLEAN>
__device__ __forceinline__ void chain2(const unsigned* m0, const unsigned* m1,
                                       f32x16& D0, f32x16& D1,
                                       unsigned mb0, unsigned mb1, int h,
                                       half8 A1v, half8 A2v) {
    if (CLEAN) {
        #pragma unroll 2
        for (int r = L_CH - 1; r >= 1; --r) {
            // all 4 loads issue back-to-back; chain1's packs fill chain0's MFMA shadow
            const uint4 su0 = *(const uint4*)(m0 + r * 16 + h * 8);
            const uint4 sv0 = *(const uint4*)(m0 + r * 16 + h * 8 + 4);
            const uint4 su1 = *(const uint4*)(m1 + r * 16 + h * 8);
            const uint4 sv1 = *(const uint4*)(m1 + r * 16 + h * 8 + 4);
            D0 = packmm(D0, su0, sv0, A1v, A2v);
            D1 = packmm(D1, su1, sv1, A1v, A2v);
        }
        if (mb0 & 1u) step1(D0, m0, 0, h, A1v, A2v);   // chunk 0 has bit0 cleared
        if (mb1 & 1u) step1(D1, m1, 0, h, A1v, A2v);
    } else {
        for (int r = L_CH - 1; r >= 0; --r) {
            if ((mb0 >> r) & 1u) step1(D0, m0, r, h, A1v, A2v);
            if ((mb1 >> r) & 1u) step1(D1, m1, r, h, A1v, A2v);
        }
    }
}

__global__ __attribute__((amdgpu_flat_work_group_size(512, 512),
                          amdgpu_waves_per_eu(4, 4)))
void crf_fused(
    const float* __restrict__ em, const int* __restrict__ tags,
    const float* __restrict__ mask, const float* __restrict__ trans,
    const float* __restrict__ startT, const float* __restrict__ endT,
    float* __restrict__ wspart, float* __restrict__ out)
{
    __shared__ unsigned elds[C_CH][512];   // 64 KiB: scales, reused for fragments

    const int wib  = threadIdx.x >> 6;     // 0..7
    const int lane = threadIdx.x & 63;
    const int n    = lane & 31;
    const int h    = lane >> 5;
    const int b    = blockIdx.x;
    const int c0   = wib * 4;              // this wave's first chunk

    // ---- issue pair-0 emission loads immediately (16B/lane, linear) ----
    float4 P0[4], P1[4];
    {
        const float4* eq0 = (const float4*)(em + ((size_t)b * S_N + (c0 + 0) * L_CH) * T_N);
        const float4* eq1 = (const float4*)(em + ((size_t)b * S_N + (c0 + 1) * L_CH) * T_N);
        #pragma unroll
        for (int i = 0; i < 4; ++i) P0[i] = eq0[i * 64 + lane];
        #pragma unroll
        for (int i = 0; i < 4; ++i) P1[i] = eq1[i * 64 + lane];
    }

    // ---- mask ballots (4 chunks = 128 positions) + path-score partial ----
    // (these scattered loads overlap the emission prefetch in flight)
    unsigned mb_[4];
    {
        float vacc = 0.f, macc = 0.f;
        #pragma unroll
        for (int q2 = 0; q2 < 2; ++q2) {
            const int s  = c0 * L_CH + q2 * 64 + lane;
            const float mv = mask[b * S_N + s];
            const unsigned long long mb = __ballot(mv != 0.0f);
            mb_[2 * q2]     = (unsigned)mb;
            mb_[2 * q2 + 1] = (unsigned)(mb >> 32);
            const int tc = tags[b * S_N + s];
            int tp = __shfl_up(tc, 1, 64);
            float val;
            if (lane == 0) {
                if (s == 0) {
                    val = startT[tc] + em[(size_t)b * S_N * T_N + tc];
                } else {
                    tp = tags[b * S_N + s - 1];
                    val = mv * (em[((size_t)b * S_N + s) * T_N + tc] + trans[tp * 32 + tc]);
                }
            } else {
                val = mv * (em[((size_t)b * S_N + s) * T_N + tc] + trans[tp * 32 + tc]);
            }
            vacc += val; macc += mv;
        }
        if (c0 == 0) mb_[0] &= ~1u;        // t=0 has no transition matrix
        #pragma unroll
        for (int d = 32; d > 0; d >>= 1) {
            vacc += __shfl_xor(vacc, d, 64);
            macc += __shfl_xor(macc, d, 64);
        }
        if (lane == 0) {
            float* slot = wspart + (size_t)b * 32 + wib * 4;
            slot[0] = vacc;
            slot[1] = macc;
            slot[2] = (float)(__popc(mb_[0]) + __popc(mb_[1]) +
                              __popc(mb_[2]) + __popc(mb_[3]));
        }
    }

    // ---- loop-invariant A fragments: f16(exp(trans)), PI-permuted cols ----
    unsigned A1[4], A2[4];
    #pragma unroll
    for (int j = 0; j < 4; ++j) {
        const int k1 = PIx(8 * h + 2 * j);
        const int k2 = PIx(16 + 8 * h + 2 * j);
        A1[j] = pkrtz(__expf(trans[n * 32 + k1]), __expf(trans[n * 32 + k1 + 1]));
        A2[j] = pkrtz(__expf(trans[n * 32 + k2]), __expf(trans[n * 32 + k2 + 1]));
    }
    const half8 A1v = mkh8(A1), A2v = mkh8(A2);

    // pack loaded f32 quads -> f16 scale pairs in D-reg-pair LDS order.
    // lane's float4 covers floats [f*4, f*4+3] of row r=f>>3; the two packed
    // u32s land at slots m and m+1, m = ((f&1)<<3)|(f&6)  (inverse of the
    // old per-slot base permutation) -> single 8B-aligned ds_write_b64.
    #define PACKQ(P, qc) { \
        unsigned* mq = elds[qc]; \
        _Pragma("unroll") \
        for (int i = 0; i < 4; ++i) { \
            const int f = i * 64 + lane; \
            const int r_ = f >> 3; \
            const int m_ = ((f & 1) << 3) | (f & 6); \
            const unsigned pk0 = pkrtz(__expf(P[i].x) * SCALE_MUL, __expf(P[i].y) * SCALE_MUL); \
            const unsigned pk1 = pkrtz(__expf(P[i].z) * SCALE_MUL, __expf(P[i].w) * SCALE_MUL); \
            *(uint2*)(mq + r_ * 16 + m_) = make_uint2(pk0, pk1); \
        } }

    PACKQ(P0, c0)
    PACKQ(P1, c0 + 1)

    // ---- issue pair-1 loads NOW; they fly under chain2(pair0) ----
    {
        const float4* eq2 = (const float4*)(em + ((size_t)b * S_N + (c0 + 2) * L_CH) * T_N);
        const float4* eq3 = (const float4*)(em + ((size_t)b * S_N + (c0 + 3) * L_CH) * T_N);
        #pragma unroll
        for (int i = 0; i < 4; ++i) P0[i] = eq2[i * 64 + lane];
        #pragma unroll
        for (int i = 0; i < 4; ++i) P1[i] = eq3[i * 64 + lane];
    }

    // ---- chain states: identity in C layout ----
    f32x16 D0, D1;
    #pragma unroll
    for (int i = 0; i < 16; ++i) {
        const int row = (i & 3) + 8 * (i >> 2) + 4 * h;
        const float v = (row == n) ? 1.0f : 0.0f;
        D0[i] = v; D1[i] = v;
    }

    const bool clean0 =
        ((mb_[0] | (c0 == 0 ? 1u : 0u)) == 0xFFFFFFFFu) && (mb_[1] == 0xFFFFFFFFu);
    const bool clean1 = (mb_[2] == 0xFFFFFFFFu) && (mb_[3] == 0xFFFFFFFFu);

    if (clean0) chain2<true >(elds[c0], elds[c0 + 1], D0, D1, mb_[0], mb_[1], h, A1v, A2v);
    else        chain2<false>(elds[c0], elds[c0 + 1], D0, D1, mb_[0], mb_[1], h, A1v, A2v);

    // fragment store: own LDS rows (scales dead), dense SoA, stride-16B
    #define STOREF(D, qc) { \
        unsigned* dst = elds[qc]; \
        ((uint4*)dst)[lane]      = make_uint4(pkrtz(D[0], D[1]),   pkrtz(D[2], D[3]), \
                                              pkrtz(D[4], D[5]),   pkrtz(D[6], D[7])); \
        ((uint4*)dst)[64 + lane] = make_uint4(pkrtz(D[8], D[9]),   pkrtz(D[10], D[11]), \
                                              pkrtz(D[12], D[13]), pkrtz(D[14], D[15])); \
    }
    STOREF(D0, c0) STOREF(D1, c0 + 1)

    // ---- pair 1: pack (consumes prefetch), re-init D, chain, store ----
    PACKQ(P0, c0 + 2)
    PACKQ(P1, c0 + 3)
    #pragma unroll
    for (int i = 0; i < 16; ++i) {
        const int row = (i & 3) + 8 * (i >> 2) + 4 * h;
        const float v = (row == n) ? 1.0f : 0.0f;
        D0[i] = v; D1[i] = v;
    }
    if (clean1) chain2<true >(elds[c0 + 2], elds[c0 + 3], D0, D1, mb_[2], mb_[3], h, A1v, A2v);
    else        chain2<false>(elds[c0 + 2], elds[c0 + 3], D0, D1, mb_[2], mb_[3], h, A1v, A2v);
    STOREF(D0, c0 + 2) STOREF(D1, c0 + 3)
    #undef STOREF
    #undef PACKQ

    __syncthreads();                        // all fragments + ws slots visible

    if (wib != 0) return;

    // ---- combine: 32-step alpha chain over LDS fragments ----
    // normalization every 4th iter, applied immediately (stable):
    // A<=1 after each norm; per-step growth <= ln(32*65504)=14.6 ln-units,
    // worst intermediate e^58.3 ~ 2e25 << f32 max. Lacc accumulates exactly
    // the applied logs. 24/32 iters skip the 5-deep shfl max + rcp + logf.
    int idxA[8], idxB[8];
    #pragma unroll
    for (int j = 0; j < 8; ++j) {
        idxA[j] = PIx(8 * h + j);
        idxB[j] = PIx(16 + 8 * h + j);
    }

    float a0 = startT[n] + em[(size_t)b * S_N * T_N + n];
    float mx = a0;
    #pragma unroll
    for (int d = 16; d > 0; d >>= 1) mx = fmaxf(mx, __shfl_xor(mx, d, 32));
    float A = __expf(a0 - mx);
    float Lacc = mx;
    float scor = (lane < 8) ? wspart[(size_t)b * 32 + lane * 4]     : 0.0f;
    float msum = (lane < 8) ? wspart[(size_t)b * 32 + lane * 4 + 1] : 0.0f;
    float ntot = (lane < 8) ? wspart[(size_t)b * 32 + lane * 4 + 2] : 0.0f;

    #pragma unroll 4
    for (int c = 0; c < C_CH; ++c) {
        const unsigned* ch = elds[c];
        const uint4 qa = *(const uint4*)(ch + lane * 4);
        const uint4 qb = *(const uint4*)(ch + 256 + lane * 4);

        float p0 = 0.f, p1 = 0.f, p2 = 0.f, p3 = 0.f;
        p0 = fmaf(__shfl(A, idxA[0], 32), hlo(qa.x), p0);
        p1 = fmaf(__shfl(A, idxA[1], 32), hhi(qa.x), p1);
        p2 = fmaf(__shfl(A, idxA[2], 32), hlo(qa.y), p2);
        p3 = fmaf(__shfl(A, idxA[3], 32), hhi(qa.y), p3);
        p0 = fmaf(__shfl(A, idxA[4], 32), hlo(qa.z), p0);
        p1 = fmaf(__shfl(A, idxA[5], 32), hhi(qa.z), p1);
        p2 = fmaf(__shfl(A, idxA[6], 32), hlo(qa.w), p2);
        p3 = fmaf(__shfl(A, idxA[7], 32), hhi(qa.w), p3);
        p0 = fmaf(__shfl(A, idxB[0], 32), hlo(qb.x), p0);
        p1 = fmaf(__shfl(A, idxB[1], 32), hhi(qb.x), p1);
        p2 = fmaf(__shfl(A, idxB[2], 32), hlo(qb.y), p2);
        p3 = fmaf(__shfl(A, idxB[3], 32), hhi(qb.y), p3);
        p0 = fmaf(__shfl(A, idxB[4], 32), hlo(qb.z), p0);
        p1 = fmaf(__shfl(A, idxB[5], 32), hhi(qb.z), p1);
        p2 = fmaf(__shfl(A, idxB[6], 32), hlo(qb.w), p2);
        p3 = fmaf(__shfl(A, idxB[7], 32), hhi(qb.w), p3);
        float part = (p0 + p1) + (p2 + p3);
        part += __shfl_xor(part, 32);       // fold half-wave partials

        if ((c & 3) == 3) {                 // static predicate (x4 unroll)
            float mm = part;
            #pragma unroll
            for (int d = 16; d > 0; d >>= 1) mm = fmaxf(mm, __shfl_xor(mm, d, 32));
            A = part * __builtin_amdgcn_rcpf(mm);
            Lacc += __logf(mm);
        } else {
            A = part;                       // unnormalized, hard-bounded
        }
    }

    float v = A * __expf(endT[n]);
    #pragma unroll
    for (int d = 16; d > 0; d >>= 1) {
        v    += __shfl_xor(v, d, 32);
        ntot += __shfl_xor(ntot, d, 32);
        msum += __shfl_xor(msum, d, 32);
        scor += __shfl_xor(scor, d, 32);
    }
    if (lane == 0) {
        const int len = (int)(msum + 0.5f);
        const int lt  = tags[b * S_N + len - 1];
        const float res = Lacc + __logf(v) + ntot * SCALE_LOG - endT[lt] - scor;
        atomicAdd(out, res);
    }
}

extern "C" void kernel_launch(void* const* d_in, const int* in_sizes, int n_in,
                              void* d_out, int out_size, void* d_ws, size_t ws_size,
                              hipStream_t stream) {
    const float* em     = (const float*)d_in[0];
    const int*   tags   = (const int*)  d_in[1];
    const float* mask   = (const float*)d_in[2];
    const float* trans  = (const float*)d_in[3];
    const float* startT = (const float*)d_in[4];
    const float* endT   = (const float*)d_in[5];

    hipMemsetAsync(d_out, 0, sizeof(float), stream);

    // one block per batch: 8 waves x 4 chunks; 64 KiB LDS -> 2 blocks/CU
    hipLaunchKernelGGL(crf_fused, dim3(B_N), dim3(512), 0, stream,
                       em, tags, mask, trans, startT, endT,
                       (float*)d_ws, (float*)d_out);
}